// Round 17
// baseline (180.834 us; speedup 1.0000x reference)
//
#include <hip/hip_runtime.h>
#include <hip/hip_bf16.h>

#define N_NODES 50000
#define N_EDGES 800000
#define CAP 96         // per-node bucket capacity (Poisson(16): P(deg>=96) ~ 1e-40)
#define M_PAD 50048
#define GBLOCKS 391    // M_PAD/128
#define EBLOCKS 3125   // N_EDGES/256
#define WBLOCKS 32     // 65536/2048

typedef __attribute__((ext_vector_type(8))) short short8;
typedef __attribute__((ext_vector_type(4))) float f32x4;

#define AS1C(p) ((const __attribute__((address_space(1))) void*)(p))
#define AS3(p)  ((__attribute__((address_space(3))) void*)(p))

__device__ __forceinline__ unsigned short f2bf(float f) {
    unsigned u = __float_as_uint(f);
    unsigned r = (u + 0x7FFFu + ((u >> 16) & 1u)) >> 16;  // RNE
    return (unsigned short)r;
}
__device__ __forceinline__ float bflo(unsigned u) { return __uint_as_float(u << 16); }
__device__ __forceinline__ float bfhi(unsigned u) { return __uint_as_float(u & 0xFFFF0000u); }

// LeakyReLU(0.2) then exp
__device__ __forceinline__ float edgew(float a) {
    a = (a >= 0.f) ? a : 0.2f * a;
    return __expf(a);
}

// ---------------- prep: W->bf16 (32 blocks) || bucket scatter (3125 blocks) -------------
// No LDS -> scatter blocks get full occupancy (fused version starved them at 48KB/block).
// cnt zeroed by the preceding memset on the same stream.
__global__ __launch_bounds__(256) void prep(const float* __restrict__ W,
                                            unsigned short* __restrict__ Wb,
                                            const int* __restrict__ ei,
                                            unsigned* __restrict__ cnt,
                                            unsigned* __restrict__ srcs) {
    int b = blockIdx.x;
    if (b < WBLOCKS) {
        size_t g = ((size_t)b * 256 + threadIdx.x) * 8;
        f32x4 v0 = *(const f32x4*)(W + g);
        f32x4 v1 = *(const f32x4*)(W + g + 4);
        short8 o;
        o[0] = (short)f2bf(v0[0]); o[1] = (short)f2bf(v0[1]);
        o[2] = (short)f2bf(v0[2]); o[3] = (short)f2bf(v0[3]);
        o[4] = (short)f2bf(v1[0]); o[5] = (short)f2bf(v1[1]);
        o[6] = (short)f2bf(v1[2]); o[7] = (short)f2bf(v1[3]);
        *(short8*)(Wb + g) = o;
    } else {
        int e = (b - WBLOCKS) * 256 + threadIdx.x;  // covers exactly N_EDGES
        int dst = ei[N_EDGES + e];
        unsigned slot = (unsigned)dst * CAP + atomicAdd(&cnt[dst], 1u);
        srcs[slot] = (unsigned)ei[e];
    }
}

// ---------------- GEMM 128x256 tile, BK=64 (+score epilogue) — R13-exact, pure ----------
__global__ __launch_bounds__(256, 3) void gemm_tile(const float* __restrict__ Xf,
                                                    const unsigned short* __restrict__ Wb,
                                                    unsigned short* __restrict__ Hb,
                                                    const float* __restrict__ a_src,
                                                    const float* __restrict__ a_dst,
                                                    float* __restrict__ s_src,
                                                    float* __restrict__ s_dst) {
    __shared__ __align__(16) unsigned short Alds[128 * 64];  // 16 KB
    __shared__ __align__(16) unsigned short Blds[256 * 64];  // 32 KB

    const int tid = threadIdx.x;
    const int wid = tid >> 6, lane = tid & 63;
    const int l15 = lane & 15, kg = lane >> 4;
    const int brow = blockIdx.x * 128;
    const int wr = wid >> 1, wc = wid & 1;

    float av[8], dv[8];
    #pragma unroll
    for (int nn = 0; nn < 8; ++nn) {
        int c = wc * 128 + nn * 16 + l15;
        av[nn] = a_src[c];
        dv[nn] = a_dst[c];
    }

    unsigned arow[4], acol[4], aaddr[4];
    bool aok[4];
    #pragma unroll
    for (int j = 0; j < 4; ++j) {
        unsigned E = (j * 256 + tid) * 8;
        unsigned r = E >> 6, c0 = E & 63;
        arow[j] = r; acol[j] = c0;
        aaddr[j] = r * 128 + ((c0 * 2) ^ ((r & 7) << 4));
        aok[j] = (brow + (int)r) < N_NODES;
    }
    unsigned rb[8], kb[8];
    #pragma unroll
    for (int j = 0; j < 8; ++j) {
        unsigned L = wid * 8192 + j * 1024 + lane * 16;
        unsigned row = L >> 7, slot = (L >> 4) & 7;
        rb[j] = row; kb[j] = (slot ^ (row & 7)) * 8;
    }

    f32x4 acc[4][8];
    #pragma unroll
    for (int m = 0; m < 4; ++m)
        #pragma unroll
        for (int nn = 0; nn < 8; ++nn)
            acc[m][nn] = (f32x4){0.f, 0.f, 0.f, 0.f};

    for (int ks = 0; ks < 4; ++ks) {
        #pragma unroll
        for (int j = 0; j < 8; ++j) {
            const unsigned short* gb = Wb + (size_t)rb[j] * 256 + ks * 64 + kb[j];
            __builtin_amdgcn_global_load_lds(AS1C(gb), AS3(&Blds[(wid * 8192 + j * 1024) / 2]), 16, 0, 0);
        }
        #pragma unroll
        for (int j = 0; j < 4; ++j) {
            f32x4 v0 = {0.f, 0.f, 0.f, 0.f}, v1 = {0.f, 0.f, 0.f, 0.f};
            if (aok[j]) {
                const float* src = Xf + (size_t)(brow + arow[j]) * 256 + ks * 64 + acol[j];
                v0 = *(const f32x4*)src;
                v1 = *(const f32x4*)(src + 4);
            }
            short8 a;
            a[0] = (short)f2bf(v0[0]); a[1] = (short)f2bf(v0[1]);
            a[2] = (short)f2bf(v0[2]); a[3] = (short)f2bf(v0[3]);
            a[4] = (short)f2bf(v1[0]); a[5] = (short)f2bf(v1[1]);
            a[6] = (short)f2bf(v1[2]); a[7] = (short)f2bf(v1[3]);
            *(short8*)((char*)Alds + aaddr[j]) = a;
        }
        __syncthreads();
        #pragma unroll
        for (int kk = 0; kk < 2; ++kk) {
            short8 af[4];
            #pragma unroll
            for (int m = 0; m < 4; ++m) {
                unsigned row = wr * 64 + m * 16 + l15;
                unsigned byte = row * 128 + ((kk * 64 + kg * 16) ^ ((row & 7) << 4));
                af[m] = *(const short8*)((const char*)Alds + byte);
            }
            #pragma unroll
            for (int h2 = 0; h2 < 2; ++h2) {
                short8 bf[4];
                #pragma unroll
                for (int q = 0; q < 4; ++q) {
                    unsigned row = wc * 128 + (h2 * 4 + q) * 16 + l15;
                    unsigned byte = row * 128 + ((kk * 64 + kg * 16) ^ ((row & 7) << 4));
                    bf[q] = *(const short8*)((const char*)Blds + byte);
                }
                #pragma unroll
                for (int m = 0; m < 4; ++m)
                    #pragma unroll
                    for (int q = 0; q < 4; ++q)
                        acc[m][h2 * 4 + q] = __builtin_amdgcn_mfma_f32_16x16x32_bf16(af[m], bf[q], acc[m][h2 * 4 + q], 0, 0, 0);
            }
        }
        __syncthreads();
    }

    #pragma unroll
    for (int m = 0; m < 4; ++m) {
        #pragma unroll
        for (int i = 0; i < 4; ++i) {
            int row = brow + wr * 64 + m * 16 + kg * 4 + i;
            bool ok = row < N_NODES;
            if (ok) {
                #pragma unroll
                for (int nn = 0; nn < 8; ++nn)
                    Hb[(size_t)row * 256 + wc * 128 + nn * 16 + l15] = f2bf(acc[m][nn][i]);
            }
            float ps0 = acc[m][0][i] * av[0] + acc[m][1][i] * av[1];
            float ps1 = acc[m][2][i] * av[2] + acc[m][3][i] * av[3];
            float ps2 = acc[m][4][i] * av[4] + acc[m][5][i] * av[5];
            float ps3 = acc[m][6][i] * av[6] + acc[m][7][i] * av[7];
            float pd0 = acc[m][0][i] * dv[0] + acc[m][1][i] * dv[1];
            float pd1 = acc[m][2][i] * dv[2] + acc[m][3][i] * dv[3];
            float pd2 = acc[m][4][i] * dv[4] + acc[m][5][i] * dv[5];
            float pd3 = acc[m][6][i] * dv[6] + acc[m][7][i] * dv[7];
            #pragma unroll
            for (int o = 1; o < 16; o <<= 1) {
                ps0 += __shfl_xor(ps0, o, 16); ps1 += __shfl_xor(ps1, o, 16);
                ps2 += __shfl_xor(ps2, o, 16); ps3 += __shfl_xor(ps3, o, 16);
                pd0 += __shfl_xor(pd0, o, 16); pd1 += __shfl_xor(pd1, o, 16);
                pd2 += __shfl_xor(pd2, o, 16); pd3 += __shfl_xor(pd3, o, 16);
            }
            if (ok && l15 == 0) {
                f32x4 vs = {ps0, ps1, ps2, ps3};
                f32x4 vd = {pd0, pd1, pd2, pd3};
                *(f32x4*)(s_src + (size_t)row * 8 + wc * 4) = vs;
                *(f32x4*)(s_dst + (size_t)row * 8 + wc * 4) = vd;
            }
        }
    }
}

// ---------------- aggregation: one WAVE per node (R8-exact); bucket CSR ----------------
__global__ __launch_bounds__(256) void aggregate(const unsigned short* __restrict__ Hb,
                                                 const float* __restrict__ s_src,
                                                 const float* __restrict__ s_dst,
                                                 const unsigned* __restrict__ cnt,
                                                 const unsigned* __restrict__ srcs,
                                                 const float* __restrict__ bias,
                                                 float* __restrict__ out) {
    const int wid = threadIdx.x >> 6;
    const int l = threadIdx.x & 63;
    const int n = blockIdx.x * 4 + wid;
    const int hh = l >> 3;
    const float sd = s_dst[(size_t)n * 8 + hh];
    unsigned beg = (unsigned)n * CAP;
    unsigned end = beg + cnt[n];
    float a0 = 0.f, a1 = 0.f, a2 = 0.f, a3 = 0.f, den = 0.f;
    unsigned s = beg;
    for (; s + 8 <= end; s += 8) {
        unsigned sid[8];
        #pragma unroll
        for (int j = 0; j < 8; ++j) sid[j] = srcs[s + j];
        uint2 r[8];
        #pragma unroll
        for (int j = 0; j < 8; ++j) r[j] = *(const uint2*)(Hb + (size_t)sid[j] * 256 + l * 4);
        float w[8];
        #pragma unroll
        for (int j = 0; j < 8; ++j) w[j] = edgew(s_src[(size_t)sid[j] * 8 + hh] + sd);
        #pragma unroll
        for (int j = 0; j < 8; ++j) {
            den += w[j];
            a0 += w[j] * bflo(r[j].x); a1 += w[j] * bfhi(r[j].x);
            a2 += w[j] * bflo(r[j].y); a3 += w[j] * bfhi(r[j].y);
        }
    }
    for (; s + 4 <= end; s += 4) {
        unsigned sid[4];
        #pragma unroll
        for (int j = 0; j < 4; ++j) sid[j] = srcs[s + j];
        uint2 r[4];
        #pragma unroll
        for (int j = 0; j < 4; ++j) r[j] = *(const uint2*)(Hb + (size_t)sid[j] * 256 + l * 4);
        float w[4];
        #pragma unroll
        for (int j = 0; j < 4; ++j) w[j] = edgew(s_src[(size_t)sid[j] * 8 + hh] + sd);
        #pragma unroll
        for (int j = 0; j < 4; ++j) {
            den += w[j];
            a0 += w[j] * bflo(r[j].x); a1 += w[j] * bfhi(r[j].x);
            a2 += w[j] * bflo(r[j].y); a3 += w[j] * bfhi(r[j].y);
        }
    }
    for (; s < end; ++s) {
        unsigned s0 = srcs[s];
        uint2 r0 = *(const uint2*)(Hb + (size_t)s0 * 256 + l * 4);
        float w0 = edgew(s_src[(size_t)s0 * 8 + hh] + sd);
        den += w0;
        a0 += w0 * bflo(r0.x); a1 += w0 * bfhi(r0.x);
        a2 += w0 * bflo(r0.y); a3 += w0 * bfhi(r0.y);
    }
    float inv = 1.f / fmaxf(den, 1e-10f);
    f32x4 bv = *(const f32x4*)(bias + l * 4);
    f32x4 o;
    o[0] = a0 * inv + bv[0];
    o[1] = a1 * inv + bv[1];
    o[2] = a2 * inv + bv[2];
    o[3] = a3 * inv + bv[3];
    __builtin_nontemporal_store(o, (f32x4*)(out + (size_t)n * 256 + l * 4));
}

extern "C" void kernel_launch(void* const* d_in, const int* in_sizes, int n_in,
                              void* d_out, int out_size, void* d_ws, size_t ws_size,
                              hipStream_t stream) {
    const float* x     = (const float*)d_in[0];
    const int*   ei    = (const int*)d_in[1];     // [2, E] int32
    const float* W     = (const float*)d_in[2];   // [256, 256]
    const float* a_src = (const float*)d_in[3];   // [8, 32]
    const float* a_dst = (const float*)d_in[4];   // [8, 32]
    const float* bias  = (const float*)d_in[5];   // [256]
    float* out = (float*)d_out;

    const size_t N = N_NODES;
    unsigned short* Hb   = (unsigned short*)d_ws;          // N*256 bf16
    unsigned short* Wb   = Hb + N * 256;                   // 65536 bf16
    float* s_src         = (float*)(Wb + 65536);           // N*8
    float* s_dst         = s_src + N * 8;                  // N*8
    unsigned* srcs       = (unsigned*)(s_dst + N * 8);     // N*CAP
    unsigned* cnt        = srcs + N * CAP;                 // N

    hipMemsetAsync(cnt, 0, N * sizeof(unsigned), stream);
    prep<<<WBLOCKS + EBLOCKS, 256, 0, stream>>>(W, Wb, ei, cnt, srcs);
    gemm_tile<<<GBLOCKS, 256, 0, stream>>>(x, Wb, Hb, a_src, a_dst, s_src, s_dst);
    aggregate<<<N_NODES / 4, 256, 0, stream>>>(Hb, s_src, s_dst, cnt, srcs, bias, out);
}

// Round 18
// 126.356 us; speedup vs baseline: 1.4311x; 1.4311x over previous
//
#include <hip/hip_runtime.h>
#include <hip/hip_bf16.h>

#define N_NODES 50000
#define N_EDGES 800000
#define CAP 96         // per-node bucket capacity (Poisson(16): P(deg>=96) ~ 1e-40)
#define M_PAD 50048
#define GBLOCKS 391    // M_PAD/128
#define SBLOCKS 782    // ceil(800000/1024): scatter blocks, 4 edges/thread
#define WBLOCKS 32     // 65536/2048
#define ZBLOCKS 196    // ceil(N_NODES/256)

typedef __attribute__((ext_vector_type(8))) short short8;
typedef __attribute__((ext_vector_type(4))) float f32x4;

#define AS1C(p) ((const __attribute__((address_space(1))) void*)(p))
#define AS3(p)  ((__attribute__((address_space(3))) void*)(p))

__device__ __forceinline__ unsigned short f2bf(float f) {
    unsigned u = __float_as_uint(f);
    unsigned r = (u + 0x7FFFu + ((u >> 16) & 1u)) >> 16;  // RNE
    return (unsigned short)r;
}
__device__ __forceinline__ float bflo(unsigned u) { return __uint_as_float(u << 16); }
__device__ __forceinline__ float bfhi(unsigned u) { return __uint_as_float(u & 0xFFFF0000u); }

// LeakyReLU(0.2) then exp
__device__ __forceinline__ float edgew(float a) {
    a = (a >= 0.f) ? a : 0.2f * a;
    return __expf(a);
}

// ---------------- prep: W->bf16 + zero cnt ----------------
__global__ __launch_bounds__(256) void prep(const float* __restrict__ W,
                                            unsigned short* __restrict__ Wb,
                                            unsigned* __restrict__ cnt) {
    int b = blockIdx.x;
    if (b < WBLOCKS) {
        size_t g = ((size_t)b * 256 + threadIdx.x) * 8;
        f32x4 v0 = *(const f32x4*)(W + g);
        f32x4 v1 = *(const f32x4*)(W + g + 4);
        short8 o;
        o[0] = (short)f2bf(v0[0]); o[1] = (short)f2bf(v0[1]);
        o[2] = (short)f2bf(v0[2]); o[3] = (short)f2bf(v0[3]);
        o[4] = (short)f2bf(v1[0]); o[5] = (short)f2bf(v1[1]);
        o[6] = (short)f2bf(v1[2]); o[7] = (short)f2bf(v1[3]);
        *(short8*)(Wb + g) = o;
    } else {
        int i = (b - WBLOCKS) * 256 + threadIdx.x;
        if (i < N_NODES) cnt[i] = 0u;
    }
}

// ---------------- fused: GEMM 128x256 tile (+scores) || bucket scatter x4 MLP -----------
// R13-exact GEMM. Scatter: each thread owns 4 edges -> 4 INDEPENDENT atomic+store chains
// in flight per thread (was 1), attacking the ~70us latency-bound scatter (R17 attribution).
__global__ __launch_bounds__(256, 2) void gemm_scatter(const float* __restrict__ Xf,
                                                       const unsigned short* __restrict__ Wb,
                                                       unsigned short* __restrict__ Hb,
                                                       const float* __restrict__ a_src,
                                                       const float* __restrict__ a_dst,
                                                       float* __restrict__ s_src,
                                                       float* __restrict__ s_dst,
                                                       const int* __restrict__ ei,
                                                       unsigned* __restrict__ cnt,
                                                       unsigned* __restrict__ srcs) {
    __shared__ __align__(16) unsigned short Alds[128 * 64];  // 16 KB
    __shared__ __align__(16) unsigned short Blds[256 * 64];  // 32 KB

    if (blockIdx.x >= GBLOCKS) {
        // ---- scatter path: 4 edges/thread, independent chains ----
        int base = (blockIdx.x - GBLOCKS) * 1024 + threadIdx.x;
        int e0 = base, e1 = base + 256, e2 = base + 512, e3 = base + 768;
        int d0 = (e0 < N_EDGES) ? ei[N_EDGES + e0] : -1;
        int d1 = (e1 < N_EDGES) ? ei[N_EDGES + e1] : -1;
        int d2 = (e2 < N_EDGES) ? ei[N_EDGES + e2] : -1;
        int d3 = (e3 < N_EDGES) ? ei[N_EDGES + e3] : -1;
        unsigned s0 = 0, s1 = 0, s2 = 0, s3 = 0;
        if (d0 >= 0) s0 = (unsigned)d0 * CAP + atomicAdd(&cnt[d0], 1u);
        if (d1 >= 0) s1 = (unsigned)d1 * CAP + atomicAdd(&cnt[d1], 1u);
        if (d2 >= 0) s2 = (unsigned)d2 * CAP + atomicAdd(&cnt[d2], 1u);
        if (d3 >= 0) s3 = (unsigned)d3 * CAP + atomicAdd(&cnt[d3], 1u);
        if (d0 >= 0) srcs[s0] = (unsigned)ei[e0];
        if (d1 >= 0) srcs[s1] = (unsigned)ei[e1];
        if (d2 >= 0) srcs[s2] = (unsigned)ei[e2];
        if (d3 >= 0) srcs[s3] = (unsigned)ei[e3];
        return;
    }

    // ---- GEMM path (R13-exact) ----
    const int tid = threadIdx.x;
    const int wid = tid >> 6, lane = tid & 63;
    const int l15 = lane & 15, kg = lane >> 4;
    const int brow = blockIdx.x * 128;
    const int wr = wid >> 1, wc = wid & 1;

    float av[8], dv[8];
    #pragma unroll
    for (int nn = 0; nn < 8; ++nn) {
        int c = wc * 128 + nn * 16 + l15;
        av[nn] = a_src[c];
        dv[nn] = a_dst[c];
    }

    unsigned arow[4], acol[4], aaddr[4];
    bool aok[4];
    #pragma unroll
    for (int j = 0; j < 4; ++j) {
        unsigned E = (j * 256 + tid) * 8;
        unsigned r = E >> 6, c0 = E & 63;
        arow[j] = r; acol[j] = c0;
        aaddr[j] = r * 128 + ((c0 * 2) ^ ((r & 7) << 4));
        aok[j] = (brow + (int)r) < N_NODES;
    }
    unsigned rb[8], kb[8];
    #pragma unroll
    for (int j = 0; j < 8; ++j) {
        unsigned L = wid * 8192 + j * 1024 + lane * 16;
        unsigned row = L >> 7, slot = (L >> 4) & 7;
        rb[j] = row; kb[j] = (slot ^ (row & 7)) * 8;
    }

    f32x4 acc[4][8];
    #pragma unroll
    for (int m = 0; m < 4; ++m)
        #pragma unroll
        for (int nn = 0; nn < 8; ++nn)
            acc[m][nn] = (f32x4){0.f, 0.f, 0.f, 0.f};

    for (int ks = 0; ks < 4; ++ks) {
        #pragma unroll
        for (int j = 0; j < 8; ++j) {
            const unsigned short* gb = Wb + (size_t)rb[j] * 256 + ks * 64 + kb[j];
            __builtin_amdgcn_global_load_lds(AS1C(gb), AS3(&Blds[(wid * 8192 + j * 1024) / 2]), 16, 0, 0);
        }
        #pragma unroll
        for (int j = 0; j < 4; ++j) {
            f32x4 v0 = {0.f, 0.f, 0.f, 0.f}, v1 = {0.f, 0.f, 0.f, 0.f};
            if (aok[j]) {
                const float* src = Xf + (size_t)(brow + arow[j]) * 256 + ks * 64 + acol[j];
                v0 = *(const f32x4*)src;
                v1 = *(const f32x4*)(src + 4);
            }
            short8 a;
            a[0] = (short)f2bf(v0[0]); a[1] = (short)f2bf(v0[1]);
            a[2] = (short)f2bf(v0[2]); a[3] = (short)f2bf(v0[3]);
            a[4] = (short)f2bf(v1[0]); a[5] = (short)f2bf(v1[1]);
            a[6] = (short)f2bf(v1[2]); a[7] = (short)f2bf(v1[3]);
            *(short8*)((char*)Alds + aaddr[j]) = a;
        }
        __syncthreads();
        #pragma unroll
        for (int kk = 0; kk < 2; ++kk) {
            short8 af[4];
            #pragma unroll
            for (int m = 0; m < 4; ++m) {
                unsigned row = wr * 64 + m * 16 + l15;
                unsigned byte = row * 128 + ((kk * 64 + kg * 16) ^ ((row & 7) << 4));
                af[m] = *(const short8*)((const char*)Alds + byte);
            }
            #pragma unroll
            for (int h2 = 0; h2 < 2; ++h2) {
                short8 bf[4];
                #pragma unroll
                for (int q = 0; q < 4; ++q) {
                    unsigned row = wc * 128 + (h2 * 4 + q) * 16 + l15;
                    unsigned byte = row * 128 + ((kk * 64 + kg * 16) ^ ((row & 7) << 4));
                    bf[q] = *(const short8*)((const char*)Blds + byte);
                }
                #pragma unroll
                for (int m = 0; m < 4; ++m)
                    #pragma unroll
                    for (int q = 0; q < 4; ++q)
                        acc[m][h2 * 4 + q] = __builtin_amdgcn_mfma_f32_16x16x32_bf16(af[m], bf[q], acc[m][h2 * 4 + q], 0, 0, 0);
            }
        }
        __syncthreads();
    }

    #pragma unroll
    for (int m = 0; m < 4; ++m) {
        #pragma unroll
        for (int i = 0; i < 4; ++i) {
            int row = brow + wr * 64 + m * 16 + kg * 4 + i;
            bool ok = row < N_NODES;
            if (ok) {
                #pragma unroll
                for (int nn = 0; nn < 8; ++nn)
                    Hb[(size_t)row * 256 + wc * 128 + nn * 16 + l15] = f2bf(acc[m][nn][i]);
            }
            float ps0 = acc[m][0][i] * av[0] + acc[m][1][i] * av[1];
            float ps1 = acc[m][2][i] * av[2] + acc[m][3][i] * av[3];
            float ps2 = acc[m][4][i] * av[4] + acc[m][5][i] * av[5];
            float ps3 = acc[m][6][i] * av[6] + acc[m][7][i] * av[7];
            float pd0 = acc[m][0][i] * dv[0] + acc[m][1][i] * dv[1];
            float pd1 = acc[m][2][i] * dv[2] + acc[m][3][i] * dv[3];
            float pd2 = acc[m][4][i] * dv[4] + acc[m][5][i] * dv[5];
            float pd3 = acc[m][6][i] * dv[6] + acc[m][7][i] * dv[7];
            #pragma unroll
            for (int o = 1; o < 16; o <<= 1) {
                ps0 += __shfl_xor(ps0, o, 16); ps1 += __shfl_xor(ps1, o, 16);
                ps2 += __shfl_xor(ps2, o, 16); ps3 += __shfl_xor(ps3, o, 16);
                pd0 += __shfl_xor(pd0, o, 16); pd1 += __shfl_xor(pd1, o, 16);
                pd2 += __shfl_xor(pd2, o, 16); pd3 += __shfl_xor(pd3, o, 16);
            }
            if (ok && l15 == 0) {
                f32x4 vs = {ps0, ps1, ps2, ps3};
                f32x4 vd = {pd0, pd1, pd2, pd3};
                *(f32x4*)(s_src + (size_t)row * 8 + wc * 4) = vs;
                *(f32x4*)(s_dst + (size_t)row * 8 + wc * 4) = vd;
            }
        }
    }
}

// ---------------- aggregation: one WAVE per node (R8-exact); bucket CSR ----------------
__global__ __launch_bounds__(256) void aggregate(const unsigned short* __restrict__ Hb,
                                                 const float* __restrict__ s_src,
                                                 const float* __restrict__ s_dst,
                                                 const unsigned* __restrict__ cnt,
                                                 const unsigned* __restrict__ srcs,
                                                 const float* __restrict__ bias,
                                                 float* __restrict__ out) {
    const int wid = threadIdx.x >> 6;
    const int l = threadIdx.x & 63;
    const int n = blockIdx.x * 4 + wid;
    const int hh = l >> 3;
    const float sd = s_dst[(size_t)n * 8 + hh];
    unsigned beg = (unsigned)n * CAP;
    unsigned end = beg + cnt[n];
    float a0 = 0.f, a1 = 0.f, a2 = 0.f, a3 = 0.f, den = 0.f;
    unsigned s = beg;
    for (; s + 8 <= end; s += 8) {
        unsigned sid[8];
        #pragma unroll
        for (int j = 0; j < 8; ++j) sid[j] = srcs[s + j];
        uint2 r[8];
        #pragma unroll
        for (int j = 0; j < 8; ++j) r[j] = *(const uint2*)(Hb + (size_t)sid[j] * 256 + l * 4);
        float w[8];
        #pragma unroll
        for (int j = 0; j < 8; ++j) w[j] = edgew(s_src[(size_t)sid[j] * 8 + hh] + sd);
        #pragma unroll
        for (int j = 0; j < 8; ++j) {
            den += w[j];
            a0 += w[j] * bflo(r[j].x); a1 += w[j] * bfhi(r[j].x);
            a2 += w[j] * bflo(r[j].y); a3 += w[j] * bfhi(r[j].y);
        }
    }
    for (; s + 4 <= end; s += 4) {
        unsigned sid[4];
        #pragma unroll
        for (int j = 0; j < 4; ++j) sid[j] = srcs[s + j];
        uint2 r[4];
        #pragma unroll
        for (int j = 0; j < 4; ++j) r[j] = *(const uint2*)(Hb + (size_t)sid[j] * 256 + l * 4);
        float w[4];
        #pragma unroll
        for (int j = 0; j < 4; ++j) w[j] = edgew(s_src[(size_t)sid[j] * 8 + hh] + sd);
        #pragma unroll
        for (int j = 0; j < 4; ++j) {
            den += w[j];
            a0 += w[j] * bflo(r[j].x); a1 += w[j] * bfhi(r[j].x);
            a2 += w[j] * bflo(r[j].y); a3 += w[j] * bfhi(r[j].y);
        }
    }
    for (; s < end; ++s) {
        unsigned s0 = srcs[s];
        uint2 r0 = *(const uint2*)(Hb + (size_t)s0 * 256 + l * 4);
        float w0 = edgew(s_src[(size_t)s0 * 8 + hh] + sd);
        den += w0;
        a0 += w0 * bflo(r0.x); a1 += w0 * bfhi(r0.x);
        a2 += w0 * bflo(r0.y); a3 += w0 * bfhi(r0.y);
    }
    float inv = 1.f / fmaxf(den, 1e-10f);
    f32x4 bv = *(const f32x4*)(bias + l * 4);
    f32x4 o;
    o[0] = a0 * inv + bv[0];
    o[1] = a1 * inv + bv[1];
    o[2] = a2 * inv + bv[2];
    o[3] = a3 * inv + bv[3];
    __builtin_nontemporal_store(o, (f32x4*)(out + (size_t)n * 256 + l * 4));
}

extern "C" void kernel_launch(void* const* d_in, const int* in_sizes, int n_in,
                              void* d_out, int out_size, void* d_ws, size_t ws_size,
                              hipStream_t stream) {
    const float* x     = (const float*)d_in[0];
    const int*   ei    = (const int*)d_in[1];     // [2, E] int32
    const float* W     = (const float*)d_in[2];   // [256, 256]
    const float* a_src = (const float*)d_in[3];   // [8, 32]
    const float* a_dst = (const float*)d_in[4];   // [8, 32]
    const float* bias  = (const float*)d_in[5];   // [256]
    float* out = (float*)d_out;

    const size_t N = N_NODES;
    unsigned short* Hb   = (unsigned short*)d_ws;          // N*256 bf16
    unsigned short* Wb   = Hb + N * 256;                   // 65536 bf16
    float* s_src         = (float*)(Wb + 65536);           // N*8
    float* s_dst         = s_src + N * 8;                  // N*8
    unsigned* srcs       = (unsigned*)(s_dst + N * 8);     // N*CAP
    unsigned* cnt        = srcs + N * CAP;                 // N

    prep<<<WBLOCKS + ZBLOCKS, 256, 0, stream>>>(W, Wb, cnt);
    gemm_scatter<<<GBLOCKS + SBLOCKS, 256, 0, stream>>>(x, Wb, Hb, a_src, a_dst,
                                                        s_src, s_dst, ei, cnt, srcs);
    aggregate<<<N_NODES / 4, 256, 0, stream>>>(Hb, s_src, s_dst, cnt, srcs, bias, out);
}